// Round 16
// baseline (85.380 us; speedup 1.0000x reference)
//
#include <hip/hip_runtime.h>
#include <hip/hip_fp16.h>

#define S_LEN 1024
#define BATCH 8
#define EMB 512
#define POSD 192
#define NH 8
#define QHD 32
#define PHD 4
#define IN_DIM 544
#define QDIM 256
#define NPOS 2047  // 2*S_LEN - 1

typedef _Float16 half8 __attribute__((ext_vector_type(8)));
typedef _Float16 half4_t __attribute__((ext_vector_type(4)));
typedef _Float16 half2_t __attribute__((ext_vector_type(2)));
typedef float f32x4 __attribute__((ext_vector_type(4)));

static __device__ __forceinline__ float fdot2(half2_t a, half2_t b, float c) {
#if __has_builtin(__builtin_amdgcn_fdot2)
  return __builtin_amdgcn_fdot2(a, b, c, false);
#else
  return c + (float)a[0] * (float)b[0] + (float)a[1] * (float)b[1];
#endif
}

// ---------- wconv: Wt[n][e] = W_in[e][n] (LDS-tiled transpose), 72 blocks ----
__global__ __launch_bounds__(256) void wconv_kernel(const float* __restrict__ W_in,
                                                    _Float16* __restrict__ Wt) {
  __shared__ float T[64][65];
  const int blk = blockIdx.x;
  const int tid = threadIdx.x;
  const int bx = blk % 9;
  const int by = blk / 9;
  const int n0 = bx * 64, e0 = by * 64;
  const int r = tid >> 4, c4 = (tid & 15) * 4;
  if (n0 + c4 < IN_DIM) {
    #pragma unroll
    for (int rr = 0; rr < 64; rr += 16) {
      f32x4 v = *(const f32x4*)(W_in + (size_t)(e0 + r + rr) * IN_DIM + n0 + c4);
      T[r + rr][c4] = v[0]; T[r + rr][c4 + 1] = v[1];
      T[r + rr][c4 + 2] = v[2]; T[r + rr][c4 + 3] = v[3];
    }
  }
  __syncthreads();
  const int nl = tid >> 2, ec = (tid & 3) * 16;
  const int n = n0 + nl;
  if (n < IN_DIM) {
    half8 h0, h1;
    #pragma unroll
    for (int j = 0; j < 8; ++j) {
      h0[j] = (_Float16)T[ec + j][nl];
      h1[j] = (_Float16)T[ec + 8 + j][nl];
    }
    *(half8*)(Wt + (size_t)n * EMB + e0 + ec) = h0;
    *(half8*)(Wt + (size_t)n * EMB + e0 + ec + 8) = h1;
  }
}

// ---- projpe: blocks 0..1151 proj (R10 64x64, XCD-pinned); 1152..1407 pe-MFMA.
// pe blocks sit at high bids -> dispatch last, fill proj's tail; pe16 is only
// consumed by the NEXT launch (attn). pe depends on nothing proj writes.
__global__ __launch_bounds__(256) void projpe_kernel(const float* __restrict__ x,
                                                     const _Float16* __restrict__ Wt,
                                                     const float* __restrict__ bias,
                                                     const float* __restrict__ W_pos,
                                                     const float* __restrict__ pos_emb,
                                                     _Float16* __restrict__ q16,
                                                     _Float16* __restrict__ k16,
                                                     _Float16* __restrict__ p16,
                                                     _Float16* __restrict__ pe16) {
  __shared__ __align__(16) char smem[38400];
  const int bid = blockIdx.x;
  const int tid = threadIdx.x;
  if (bid < 1152) {
    _Float16 (*As)[40] = reinterpret_cast<_Float16(*)[40]>(smem);
    _Float16 (*Bs)[40] = reinterpret_cast<_Float16(*)[40]>(smem + 5120);
    const int xcd = bid & 7, idx = bid >> 3;
    const int mt = xcd * 16 + (idx & 15);
    const int nt = idx >> 4;
    const int m0 = mt * 64;
    const int n0 = nt * 64;
    const int w = tid >> 6, l = tid & 63, g = l >> 4, lg = l & 15;
    const int wm = w >> 1, wn = w & 1;
    const int srow = tid >> 2, sc = tid & 3;

    f32x4 acc[2][2] = {};

    for (int k0 = 0; k0 < EMB; k0 += 32) {
      const float* asrc = x + (size_t)(m0 + srow) * EMB + k0 + sc * 8;
      f32x4 a0 = *(const f32x4*)asrc;
      f32x4 a1 = *(const f32x4*)(asrc + 4);
      half8 ah;
      #pragma unroll
      for (int j = 0; j < 4; ++j) { ah[j] = (_Float16)a0[j]; ah[4 + j] = (_Float16)a1[j]; }
      int nrow = n0 + srow;
      half8 bh8 = {};
      if (nrow < IN_DIM) bh8 = *(const half8*)(Wt + (size_t)nrow * EMB + k0 + sc * 8);
      *(half8*)&As[srow][sc * 8] = ah;
      *(half8*)&Bs[srow][sc * 8] = bh8;
      __syncthreads();
      half8 aF0 = *(const half8*)&As[wm * 32 + lg][g * 8];
      half8 aF1 = *(const half8*)&As[wm * 32 + 16 + lg][g * 8];
      half8 bF0 = *(const half8*)&Bs[wn * 32 + lg][g * 8];
      half8 bF1 = *(const half8*)&Bs[wn * 32 + 16 + lg][g * 8];
      acc[0][0] = __builtin_amdgcn_mfma_f32_16x16x32_f16(aF0, bF0, acc[0][0], 0, 0, 0);
      acc[0][1] = __builtin_amdgcn_mfma_f32_16x16x32_f16(aF0, bF1, acc[0][1], 0, 0, 0);
      acc[1][0] = __builtin_amdgcn_mfma_f32_16x16x32_f16(aF1, bF0, acc[1][0], 0, 0, 0);
      acc[1][1] = __builtin_amdgcn_mfma_f32_16x16x32_f16(aF1, bF1, acc[1][1], 0, 0, 0);
      __syncthreads();
    }

    #pragma unroll
    for (int sm = 0; sm < 2; ++sm)
      #pragma unroll
      for (int sn = 0; sn < 2; ++sn)
        #pragma unroll
        for (int r = 0; r < 4; ++r) {
          int m = m0 + wm * 32 + sm * 16 + 4 * g + r;
          int n = n0 + wn * 32 + sn * 16 + lg;
          if (n < IN_DIM) {
            float v = acc[sm][sn][r] + bias[n];
            _Float16 hv = (_Float16)v;
            int s = m >> 3, b = m & 7;
            if (n < QDIM) {
              int h = n >> 5, d = n & 31;
              q16[(((size_t)(b * NH + h)) * S_LEN + s) * QHD + d] = hv;
            } else if (n < 2 * QDIM) {
              int n2 = n - QDIM;
              int h = n2 >> 5, d = n2 & 31;
              k16[(((size_t)(b * NH + h)) * S_LEN + s) * QHD + d] = hv;
            } else {
              int n2 = n - 2 * QDIM;
              int h = n2 >> 2, d = n2 & 3;
              p16[(((size_t)(b * NH + h)) * S_LEN + s) * PHD + d] = hv;
            }
          }
        }
  } else {
    // ---- pe = pos_emb @ W_pos via MFMA -> pe16[b][h][n][4] (R10 prep body) ----
    _Float16 (*As)[200] = reinterpret_cast<_Float16(*)[200]>(smem);          // 64 rows
    _Float16 (*Wl)[200] = reinterpret_cast<_Float16(*)[200]>(smem + 25600);  // 32 rows
    const int id = bid - 1152;
    const int chunk = id & 31, b = id >> 5;
    const int n0 = chunk * 64;
    #pragma unroll
    for (int p = 0; p < 6; ++p) {
      int f = (p * 256 + tid) * 4;
      f32x4 v = *(const f32x4*)(W_pos + f);
      int k = f >> 5, c = f & 31;
      #pragma unroll
      for (int t = 0; t < 4; ++t) Wl[c + t][k] = (_Float16)v[t];
    }
    const int row = tid >> 2, sc = tid & 3;
    const bool rowok = (n0 + row) < NPOS;
    const float* src = pos_emb + ((size_t)b * NPOS + n0 + row) * POSD + sc * 48;
    #pragma unroll
    for (int j = 0; j < 6; ++j) {
      f32x4 v0 = {}, v1 = {};
      if (rowok) { v0 = *(const f32x4*)(src + j * 8); v1 = *(const f32x4*)(src + j * 8 + 4); }
      half8 h;
      #pragma unroll
      for (int t = 0; t < 4; ++t) { h[t] = (_Float16)v0[t]; h[4 + t] = (_Float16)v1[t]; }
      *(half8*)&As[row][sc * 48 + j * 8] = h;
    }
    __syncthreads();
    const int w = tid >> 6, l = tid & 63, g = l >> 4, lg = l & 15;
    f32x4 acc0 = {}, acc1 = {};
    #pragma unroll
    for (int kk = 0; kk < POSD; kk += 32) {
      half8 aF = *(const half8*)&As[w * 16 + lg][kk + g * 8];
      half8 b0 = *(const half8*)&Wl[lg][kk + g * 8];
      half8 b1 = *(const half8*)&Wl[16 + lg][kk + g * 8];
      acc0 = __builtin_amdgcn_mfma_f32_16x16x32_f16(aF, b0, acc0, 0, 0, 0);
      acc1 = __builtin_amdgcn_mfma_f32_16x16x32_f16(aF, b1, acc1, 0, 0, 0);
    }
    f32x4 accs[2] = {acc0, acc1};
    #pragma unroll
    for (int t = 0; t < 2; ++t) {
      int c = t * 16 + lg, h = c >> 2, d = c & 3;
      _Float16* dst = pe16 + ((size_t)(b * NH + h) * NPOS) * PHD + d;
      #pragma unroll
      for (int r2 = 0; r2 < 4; ++r2) {
        int n = n0 + w * 16 + 4 * g + r2;
        if (n < NPOS) dst[(size_t)n * PHD] = (_Float16)accs[t][r2];
      }
    }
  }
}

// ---- attn: R15 exact (fp16 sbuf transpose + nt 256B stores) ----
__global__ __launch_bounds__(256, 4) void attn_kernel(const _Float16* __restrict__ q16,
                                                      const _Float16* __restrict__ k16,
                                                      const _Float16* __restrict__ p16,
                                                      const _Float16* __restrict__ pe16,
                                                      float* __restrict__ out) {
  __shared__ __align__(16) _Float16 peLDS[1040 * 4];   // 8.3 KB
  __shared__ float wred[4][16];
  __shared__ __align__(16) _Float16 sbufh[4][16][72];  // 9.2 KB
  const int bid = blockIdx.x;
  const int swz = (bid & 7) * 512 + (bid >> 3);  // 8 XCDs x 512 contiguous
  const int bh = swz >> 6;
  const int rblk = swz & 63;
  const int b = bh >> 3, h = bh & 7;
  const int i0 = rblk * 16;
  const int tid = threadIdx.x;
  const int w = tid >> 6, l = tid & 63, g = l >> 4, lg = l & 15;
  const int nlo = S_LEN - 16 - i0;

  for (int it = tid; it < 1039; it += 256) {
    *(uint2*)&peLDS[it * 4] =
        *(const uint2*)&pe16[((size_t)bh * NPOS + nlo + it) * 4];
  }

  const _Float16* qbase = q16 + ((size_t)bh * S_LEN + i0) * QHD;
  half8 qF = *(const half8*)(qbase + lg * QHD + g * 8);

  const _Float16* pbase = p16 + ((size_t)bh * S_LEN + i0 + lg) * PHD;
  half2_t pq0 = *(const half2_t*)(pbase);
  half2_t pq1 = *(const half2_t*)(pbase + 2);

  __syncthreads();

  const _Float16* kbase = k16 + (size_t)bh * S_LEN * QHD;
  const int jw = w * 256;
  f32x4 zero = {};
  float s = 0.f;
  half4_t probs[16];

  #pragma unroll
  for (int ct = 0; ct < 16; ++ct) {
    int j = jw + ct * 16 + lg;
    half8 kF = *(const half8*)(kbase + (size_t)j * QHD + g * 8);
    f32x4 a = __builtin_amdgcn_mfma_f32_16x16x32_f16(kF, qF, zero, 0, 0, 0);
    int nl0 = 15 - lg + jw + ct * 16 + 4 * g;
    half4_t ph;
    #pragma unroll
    for (int r = 0; r < 4; ++r) {
      half4_t pv4 = *(const half4_t*)&peLDS[(nl0 + r) * 4];
      half2_t lo = {pv4[0], pv4[1]};
      half2_t hi = {pv4[2], pv4[3]};
      float sc = fdot2(pq1, hi, fdot2(pq0, lo, a[r]));
      float e = __expf(sc - 6.0f);
      s += e;
      ph[r] = (_Float16)e;
    }
    probs[ct] = ph;
  }

  s += __shfl_xor(s, 16);
  s += __shfl_xor(s, 32);
  if (g == 0) wred[w][lg] = s;
  __syncthreads();
  s = (wred[0][lg] + wred[1][lg]) + (wred[2][lg] + wred[3][lg]);
  const _Float16 hinv = (_Float16)(1.0f / s);

  const size_t orow0 = ((size_t)(h * BATCH + b) * S_LEN + i0) * S_LEN;
  #pragma unroll
  for (int chunk = 0; chunk < 4; ++chunk) {
    #pragma unroll
    for (int cc = 0; cc < 4; ++cc) {
      half4_t ph = probs[chunk * 4 + cc];
      half4_t pn;
      #pragma unroll
      for (int r = 0; r < 4; ++r) pn[r] = ph[r] * hinv;  // v_pk_mul_f16
      *(half4_t*)&sbufh[w][lg][cc * 16 + 4 * g] = pn;
    }
    asm volatile("s_waitcnt lgkmcnt(0)" ::: "memory");
    __builtin_amdgcn_sched_barrier(0);
    #pragma unroll
    for (int k2 = 0; k2 < 4; ++k2) {
      int rr = k2 * 4 + g;
      half4_t hv = *(const half4_t*)&sbufh[w][rr][lg * 4];
      f32x4 v;
      #pragma unroll
      for (int r = 0; r < 4; ++r) v[r] = (float)hv[r];
      __builtin_nontemporal_store(
          v, (f32x4*)(out + orow0 + (size_t)rr * S_LEN + jw + chunk * 64 + lg * 4));
    }
    asm volatile("s_waitcnt lgkmcnt(0)" ::: "memory");
    __builtin_amdgcn_sched_barrier(0);
  }
}

extern "C" void kernel_launch(void* const* d_in, const int* in_sizes, int n_in,
                              void* d_out, int out_size, void* d_ws, size_t ws_size,
                              hipStream_t stream) {
  const float* x = (const float*)d_in[0];
  const float* pos_emb = (const float*)d_in[1];
  const float* W_in = (const float*)d_in[2];
  const float* b_in = (const float*)d_in[3];
  const float* W_pos = (const float*)d_in[4];
  float* out = (float*)d_out;

  char* ws = (char*)d_ws;
  _Float16* Wt = (_Float16*)(ws);                                   // 557056 B
  _Float16* q16 = (_Float16*)(ws + 557056);                         // 4 MB
  _Float16* k16 = (_Float16*)(ws + 557056 + 4194304);               // 4 MB
  _Float16* p16 = (_Float16*)(ws + 557056 + 2 * 4194304);           // 512 KB
  _Float16* pe16 = (_Float16*)(ws + 557056 + 2 * 4194304 + 524288); // ~1 MB

  wconv_kernel<<<dim3(72), dim3(256), 0, stream>>>(W_in, Wt);
  projpe_kernel<<<dim3(1408), dim3(256), 0, stream>>>(x, Wt, b_in, W_pos, pos_emb,
                                                      q16, k16, p16, pe16);
  attn_kernel<<<dim3(4096), dim3(256), 0, stream>>>(q16, k16, p16, pe16, out);
}

// Round 17
// 79.265 us; speedup vs baseline: 1.0771x; 1.0771x over previous
//
#include <hip/hip_runtime.h>
#include <hip/hip_fp16.h>

#define S_LEN 1024
#define BATCH 8
#define EMB 512
#define POSD 192
#define NH 8
#define QHD 32
#define PHD 4
#define IN_DIM 544
#define QDIM 256
#define NPOS 2047  // 2*S_LEN - 1

typedef _Float16 half8 __attribute__((ext_vector_type(8)));
typedef _Float16 half4_t __attribute__((ext_vector_type(4)));
typedef _Float16 half2_t __attribute__((ext_vector_type(2)));
typedef float f32x4 __attribute__((ext_vector_type(4)));

static __device__ __forceinline__ float fdot2(half2_t a, half2_t b, float c) {
#if __has_builtin(__builtin_amdgcn_fdot2)
  return __builtin_amdgcn_fdot2(a, b, c, false);
#else
  return c + (float)a[0] * (float)b[0] + (float)a[1] * (float)b[1];
#endif
}

// ---------- wconv: blocks 0..71 Wt transpose; block 72 WtP convert ----------
__global__ __launch_bounds__(256) void wconv_kernel(const float* __restrict__ W_in,
                                                    const float* __restrict__ W_pos,
                                                    _Float16* __restrict__ Wt,
                                                    _Float16* __restrict__ WtP) {
  const int blk = blockIdx.x;
  const int tid = threadIdx.x;
  if (blk < 72) {
    __shared__ float T[64][65];
    const int bx = blk % 9;
    const int by = blk / 9;
    const int n0 = bx * 64, e0 = by * 64;
    const int r = tid >> 4, c4 = (tid & 15) * 4;
    if (n0 + c4 < IN_DIM) {
      #pragma unroll
      for (int rr = 0; rr < 64; rr += 16) {
        f32x4 v = *(const f32x4*)(W_in + (size_t)(e0 + r + rr) * IN_DIM + n0 + c4);
        T[r + rr][c4] = v[0]; T[r + rr][c4 + 1] = v[1];
        T[r + rr][c4 + 2] = v[2]; T[r + rr][c4 + 3] = v[3];
      }
    }
    __syncthreads();
    const int nl = tid >> 2, ec = (tid & 3) * 16;
    const int n = n0 + nl;
    if (n < IN_DIM) {
      half8 h0, h1;
      #pragma unroll
      for (int j = 0; j < 8; ++j) {
        h0[j] = (_Float16)T[ec + j][nl];
        h1[j] = (_Float16)T[ec + 8 + j][nl];
      }
      *(half8*)(Wt + (size_t)n * EMB + e0 + ec) = h0;
      *(half8*)(Wt + (size_t)n * EMB + e0 + ec + 8) = h1;
    }
  } else {
    // WtP[c][k] = W_pos[k][c], fp16 (12 KB)
    for (int i = tid; i < 32 * POSD; i += 256) {
      int c = i / POSD, k = i % POSD;
      WtP[i] = (_Float16)W_pos[(size_t)k * 32 + c];
    }
  }
}

// ---- projpe: blocks 0..1151 proj (R10 64x64, XCD-pinned, 10.2 KB smem);
//      blocks 1152..1407 pe-MFMA with ZERO smem (A-frags direct from global,
//      B-frags from L2-resident WtP). Fused smem = 10.2 KB -> proj occupancy
//      unharmed (R16's 38.4 KB union was the regression mechanism).
__global__ __launch_bounds__(256) void projpe_kernel(const float* __restrict__ x,
                                                     const _Float16* __restrict__ Wt,
                                                     const float* __restrict__ bias,
                                                     const _Float16* __restrict__ WtP,
                                                     const float* __restrict__ pos_emb,
                                                     _Float16* __restrict__ q16,
                                                     _Float16* __restrict__ k16,
                                                     _Float16* __restrict__ p16,
                                                     _Float16* __restrict__ pe16) {
  __shared__ __align__(16) _Float16 As[64][40];
  __shared__ __align__(16) _Float16 Bs[64][40];
  const int bid = blockIdx.x;
  const int tid = threadIdx.x;
  const int w = tid >> 6, l = tid & 63, g = l >> 4, lg = l & 15;
  if (bid < 1152) {
    const int xcd = bid & 7, idx = bid >> 3;
    const int mt = xcd * 16 + (idx & 15);
    const int nt = idx >> 4;
    const int m0 = mt * 64;
    const int n0 = nt * 64;
    const int wm = w >> 1, wn = w & 1;
    const int srow = tid >> 2, sc = tid & 3;

    f32x4 acc[2][2] = {};

    for (int k0 = 0; k0 < EMB; k0 += 32) {
      const float* asrc = x + (size_t)(m0 + srow) * EMB + k0 + sc * 8;
      f32x4 a0 = *(const f32x4*)asrc;
      f32x4 a1 = *(const f32x4*)(asrc + 4);
      half8 ah;
      #pragma unroll
      for (int j = 0; j < 4; ++j) { ah[j] = (_Float16)a0[j]; ah[4 + j] = (_Float16)a1[j]; }
      int nrow = n0 + srow;
      half8 bh8 = {};
      if (nrow < IN_DIM) bh8 = *(const half8*)(Wt + (size_t)nrow * EMB + k0 + sc * 8);
      *(half8*)&As[srow][sc * 8] = ah;
      *(half8*)&Bs[srow][sc * 8] = bh8;
      __syncthreads();
      half8 aF0 = *(const half8*)&As[wm * 32 + lg][g * 8];
      half8 aF1 = *(const half8*)&As[wm * 32 + 16 + lg][g * 8];
      half8 bF0 = *(const half8*)&Bs[wn * 32 + lg][g * 8];
      half8 bF1 = *(const half8*)&Bs[wn * 32 + 16 + lg][g * 8];
      acc[0][0] = __builtin_amdgcn_mfma_f32_16x16x32_f16(aF0, bF0, acc[0][0], 0, 0, 0);
      acc[0][1] = __builtin_amdgcn_mfma_f32_16x16x32_f16(aF0, bF1, acc[0][1], 0, 0, 0);
      acc[1][0] = __builtin_amdgcn_mfma_f32_16x16x32_f16(aF1, bF0, acc[1][0], 0, 0, 0);
      acc[1][1] = __builtin_amdgcn_mfma_f32_16x16x32_f16(aF1, bF1, acc[1][1], 0, 0, 0);
      __syncthreads();
    }

    #pragma unroll
    for (int sm = 0; sm < 2; ++sm)
      #pragma unroll
      for (int sn = 0; sn < 2; ++sn)
        #pragma unroll
        for (int r = 0; r < 4; ++r) {
          int m = m0 + wm * 32 + sm * 16 + 4 * g + r;
          int n = n0 + wn * 32 + sn * 16 + lg;
          if (n < IN_DIM) {
            float v = acc[sm][sn][r] + bias[n];
            _Float16 hv = (_Float16)v;
            int s = m >> 3, b = m & 7;
            if (n < QDIM) {
              int h = n >> 5, d = n & 31;
              q16[(((size_t)(b * NH + h)) * S_LEN + s) * QHD + d] = hv;
            } else if (n < 2 * QDIM) {
              int n2 = n - QDIM;
              int h = n2 >> 5, d = n2 & 31;
              k16[(((size_t)(b * NH + h)) * S_LEN + s) * QHD + d] = hv;
            } else {
              int n2 = n - 2 * QDIM;
              int h = n2 >> 2, d = n2 & 3;
              p16[(((size_t)(b * NH + h)) * S_LEN + s) * PHD + d] = hv;
            }
          }
        }
  } else {
    // ---- pe: LDS-free. A row = n0 + w*16 + lg, k-chunk g*8 (same frag map
    // as the staged version; same fp32->fp16 rounding => bitwise-identical).
    const int id = bid - 1152;
    const int chunk = id & 31, b = id >> 5;
    const int n0 = chunk * 64;
    const int nrow = n0 + w * 16 + lg;
    const bool ok = nrow < NPOS;
    const float* arow = pos_emb + ((size_t)b * NPOS + nrow) * POSD;
    f32x4 acc0 = {}, acc1 = {};
    #pragma unroll
    for (int kk = 0; kk < POSD; kk += 32) {
      half8 aF = {};
      if (ok) {
        f32x4 a0 = *(const f32x4*)(arow + kk + g * 8);
        f32x4 a1 = *(const f32x4*)(arow + kk + g * 8 + 4);
        #pragma unroll
        for (int t = 0; t < 4; ++t) { aF[t] = (_Float16)a0[t]; aF[4 + t] = (_Float16)a1[t]; }
      }
      half8 b0 = *(const half8*)(WtP + (size_t)lg * POSD + kk + g * 8);
      half8 b1 = *(const half8*)(WtP + (size_t)(16 + lg) * POSD + kk + g * 8);
      acc0 = __builtin_amdgcn_mfma_f32_16x16x32_f16(aF, b0, acc0, 0, 0, 0);
      acc1 = __builtin_amdgcn_mfma_f32_16x16x32_f16(aF, b1, acc1, 0, 0, 0);
    }
    f32x4 accs[2] = {acc0, acc1};
    #pragma unroll
    for (int t = 0; t < 2; ++t) {
      int c = t * 16 + lg, h = c >> 2, d = c & 3;
      _Float16* dst = pe16 + ((size_t)(b * NH + h) * NPOS) * PHD + d;
      #pragma unroll
      for (int r2 = 0; r2 < 4; ++r2) {
        int n = n0 + w * 16 + 4 * g + r2;
        if (n < NPOS) dst[(size_t)n * PHD] = (_Float16)accs[t][r2];
      }
    }
  }
}

// ---- attn: R15 exact (fp16 sbuf transpose + nt 256B stores) ----
__global__ __launch_bounds__(256, 4) void attn_kernel(const _Float16* __restrict__ q16,
                                                      const _Float16* __restrict__ k16,
                                                      const _Float16* __restrict__ p16,
                                                      const _Float16* __restrict__ pe16,
                                                      float* __restrict__ out) {
  __shared__ __align__(16) _Float16 peLDS[1040 * 4];   // 8.3 KB
  __shared__ float wred[4][16];
  __shared__ __align__(16) _Float16 sbufh[4][16][72];  // 9.2 KB
  const int bid = blockIdx.x;
  const int swz = (bid & 7) * 512 + (bid >> 3);  // 8 XCDs x 512 contiguous
  const int bh = swz >> 6;
  const int rblk = swz & 63;
  const int b = bh >> 3, h = bh & 7;
  const int i0 = rblk * 16;
  const int tid = threadIdx.x;
  const int w = tid >> 6, l = tid & 63, g = l >> 4, lg = l & 15;
  const int nlo = S_LEN - 16 - i0;

  for (int it = tid; it < 1039; it += 256) {
    *(uint2*)&peLDS[it * 4] =
        *(const uint2*)&pe16[((size_t)bh * NPOS + nlo + it) * 4];
  }

  const _Float16* qbase = q16 + ((size_t)bh * S_LEN + i0) * QHD;
  half8 qF = *(const half8*)(qbase + lg * QHD + g * 8);

  const _Float16* pbase = p16 + ((size_t)bh * S_LEN + i0 + lg) * PHD;
  half2_t pq0 = *(const half2_t*)(pbase);
  half2_t pq1 = *(const half2_t*)(pbase + 2);

  __syncthreads();

  const _Float16* kbase = k16 + (size_t)bh * S_LEN * QHD;
  const int jw = w * 256;
  f32x4 zero = {};
  float s = 0.f;
  half4_t probs[16];

  #pragma unroll
  for (int ct = 0; ct < 16; ++ct) {
    int j = jw + ct * 16 + lg;
    half8 kF = *(const half8*)(kbase + (size_t)j * QHD + g * 8);
    f32x4 a = __builtin_amdgcn_mfma_f32_16x16x32_f16(kF, qF, zero, 0, 0, 0);
    int nl0 = 15 - lg + jw + ct * 16 + 4 * g;
    half4_t ph;
    #pragma unroll
    for (int r = 0; r < 4; ++r) {
      half4_t pv4 = *(const half4_t*)&peLDS[(nl0 + r) * 4];
      half2_t lo = {pv4[0], pv4[1]};
      half2_t hi = {pv4[2], pv4[3]};
      float sc = fdot2(pq1, hi, fdot2(pq0, lo, a[r]));
      float e = __expf(sc - 6.0f);
      s += e;
      ph[r] = (_Float16)e;
    }
    probs[ct] = ph;
  }

  s += __shfl_xor(s, 16);
  s += __shfl_xor(s, 32);
  if (g == 0) wred[w][lg] = s;
  __syncthreads();
  s = (wred[0][lg] + wred[1][lg]) + (wred[2][lg] + wred[3][lg]);
  const _Float16 hinv = (_Float16)(1.0f / s);

  const size_t orow0 = ((size_t)(h * BATCH + b) * S_LEN + i0) * S_LEN;
  #pragma unroll
  for (int chunk = 0; chunk < 4; ++chunk) {
    #pragma unroll
    for (int cc = 0; cc < 4; ++cc) {
      half4_t ph = probs[chunk * 4 + cc];
      half4_t pn;
      #pragma unroll
      for (int r = 0; r < 4; ++r) pn[r] = ph[r] * hinv;  // v_pk_mul_f16
      *(half4_t*)&sbufh[w][lg][cc * 16 + 4 * g] = pn;
    }
    asm volatile("s_waitcnt lgkmcnt(0)" ::: "memory");
    __builtin_amdgcn_sched_barrier(0);
    #pragma unroll
    for (int k2 = 0; k2 < 4; ++k2) {
      int rr = k2 * 4 + g;
      half4_t hv = *(const half4_t*)&sbufh[w][rr][lg * 4];
      f32x4 v;
      #pragma unroll
      for (int r = 0; r < 4; ++r) v[r] = (float)hv[r];
      __builtin_nontemporal_store(
          v, (f32x4*)(out + orow0 + (size_t)rr * S_LEN + jw + chunk * 64 + lg * 4));
    }
    asm volatile("s_waitcnt lgkmcnt(0)" ::: "memory");
    __builtin_amdgcn_sched_barrier(0);
  }
}

extern "C" void kernel_launch(void* const* d_in, const int* in_sizes, int n_in,
                              void* d_out, int out_size, void* d_ws, size_t ws_size,
                              hipStream_t stream) {
  const float* x = (const float*)d_in[0];
  const float* pos_emb = (const float*)d_in[1];
  const float* W_in = (const float*)d_in[2];
  const float* b_in = (const float*)d_in[3];
  const float* W_pos = (const float*)d_in[4];
  float* out = (float*)d_out;

  char* ws = (char*)d_ws;
  _Float16* Wt = (_Float16*)(ws);                                   // 557056 B
  _Float16* q16 = (_Float16*)(ws + 557056);                         // 4 MB
  _Float16* k16 = (_Float16*)(ws + 557056 + 4194304);               // 4 MB
  _Float16* p16 = (_Float16*)(ws + 557056 + 2 * 4194304);           // 512 KB
  _Float16* pe16 = (_Float16*)(ws + 557056 + 2 * 4194304 + 524288); // 1048064 B
  // WtP gets its OWN slot (cannot alias p16: pe reads WtP while proj writes
  // p16 concurrently inside projpe_kernel).
  _Float16* WtP = (_Float16*)(ws + 557056 + 2 * 4194304 + 524288 + 1048576); // 12 KB

  wconv_kernel<<<dim3(73), dim3(256), 0, stream>>>(W_in, W_pos, Wt, WtP);
  projpe_kernel<<<dim3(1408), dim3(256), 0, stream>>>(x, Wt, b_in, WtP, pos_emb,
                                                      q16, k16, p16, pe16);
  attn_kernel<<<dim3(4096), dim3(256), 0, stream>>>(q16, k16, p16, pe16, out);
}